// Round 4
// baseline (83.997 us; speedup 1.0000x reference)
//
#include <hip/hip_runtime.h>

#define IMG   256
#define ROWS  32    // output rows per block (strip)
#define KS    29
#define PAD   14
#define LDSS  284   // floats per LDS row = 71 float4; 71 mod 8 == 7 -> lane-per-row b128 reads conflict-free

// exp(-d^2/(2*49)) for d=0..14; normalization folds at compile time.
static constexpr float GK[15] = {
    1.0f,        0.98984780f, 0.96000544f, 0.91225408f, 0.84936581f,
    0.77483743f, 0.69256933f, 0.60653066f, 0.52045012f, 0.43756474f,
    0.36044779f, 0.29092381f, 0.23006630f, 0.17826398f, 0.13533528f
};
static constexpr float GSUM =
    GK[0] + 2.0f * (GK[1] + GK[2] + GK[3] + GK[4] + GK[5] + GK[6] + GK[7] +
                    GK[8] + GK[9] + GK[10] + GK[11] + GK[12] + GK[13] + GK[14]);
static constexpr float WT[29] = {
    GK[14]/GSUM, GK[13]/GSUM, GK[12]/GSUM, GK[11]/GSUM, GK[10]/GSUM, GK[9]/GSUM, GK[8]/GSUM,
    GK[7]/GSUM,  GK[6]/GSUM,  GK[5]/GSUM,  GK[4]/GSUM,  GK[3]/GSUM,  GK[2]/GSUM, GK[1]/GSUM,
    GK[0]/GSUM,
    GK[1]/GSUM,  GK[2]/GSUM,  GK[3]/GSUM,  GK[4]/GSUM,  GK[5]/GSUM,  GK[6]/GSUM, GK[7]/GSUM,
    GK[8]/GSUM,  GK[9]/GSUM,  GK[10]/GSUM, GK[11]/GSUM, GK[12]/GSUM, GK[13]/GSUM, GK[14]/GSUM
};

__device__ __forceinline__ int refl(int p) {
    int a = p < 0 ? -p : p;        // reflect at 0
    int b = 2 * (IMG - 1) - a;     // reflect at 255
    return a < b ? a : b;
}

__global__ __launch_bounds__(512, 8)
void gauss_v4(const float* __restrict__ x, float* __restrict__ out) {
    __shared__ float s[ROWS * LDSS];   // 36,352 B -> 4 blocks/CU (145.4 KB of 160)

    const int t   = threadIdx.x;
    const int img = blockIdx.y;
    const int y0  = blockIdx.x * ROWS;

    const float* __restrict__ src = x   + (size_t)img * (IMG * IMG);
    float*       __restrict__ dst = out + (size_t)img * (IMG * IMG);

    // ---- Phase A: vertical conv, global(float4) -> LDS.
    //      thread = (colquad cq 0..63, rowgroup rg 0..7); rg is wave-uniform.
    {
        const int cq   = t & 63;
        const int rg   = t >> 6;
        const int c0   = cq * 4;
        const int brow = y0 + rg * 4 - PAD;   // first of 32 input rows

        float4 acc[4];
        #pragma unroll
        for (int j = 0; j < 4; ++j) acc[j] = make_float4(0.f, 0.f, 0.f, 0.f);

        if (brow >= 0 && brow + 31 < IMG) {
            // interior: 32 independent coalesced float4 loads, pointer-walk
            const float* p = src + (size_t)brow * IMG + c0;
            #pragma unroll
            for (int sdx = 0; sdx < 32; ++sdx) {
                const float4 v = *(const float4*)(p + sdx * IMG);
                #pragma unroll
                for (int j = 0; j < 4; ++j) {
                    const int k = sdx - j;
                    if (k >= 0 && k < KS) {
                        acc[j].x += WT[k] * v.x;
                        acc[j].y += WT[k] * v.y;
                        acc[j].z += WT[k] * v.z;
                        acc[j].w += WT[k] * v.w;
                    }
                }
            }
        } else {
            // boundary rowgroups (8 of 64 wave-groups): reflected, wave-uniform rows
            #pragma unroll
            for (int sdx = 0; sdx < 32; ++sdx) {
                const float4 v = *(const float4*)(src + (size_t)refl(brow + sdx) * IMG + c0);
                #pragma unroll
                for (int j = 0; j < 4; ++j) {
                    const int k = sdx - j;
                    if (k >= 0 && k < KS) {
                        acc[j].x += WT[k] * v.x;
                        acc[j].y += WT[k] * v.y;
                        acc[j].z += WT[k] * v.z;
                        acc[j].w += WT[k] * v.w;
                    }
                }
            }
        }

        // main stores: lanes write consecutive addresses (8B-aligned float2 pairs)
        #pragma unroll
        for (int j = 0; j < 4; ++j) {
            float* row = &s[(rg * 4 + j) * LDSS + PAD + c0];
            *(float2*)(row)     = make_float2(acc[j].x, acc[j].y);
            *(float2*)(row + 2) = make_float2(acc[j].z, acc[j].w);
        }
        // mirrored horizontal halo (reflect-101), only edge quads take this
        if (c0 <= PAD || c0 >= IMG - 1 - PAD - 3) {
            #pragma unroll
            for (int q = 0; q < 4; ++q) {
                const int c = c0 + q;
                if (c >= 1 && c <= PAD) {
                    #pragma unroll
                    for (int j = 0; j < 4; ++j) {
                        const float v = q == 0 ? acc[j].x : q == 1 ? acc[j].y : q == 2 ? acc[j].z : acc[j].w;
                        s[(rg * 4 + j) * LDSS + (PAD - c)] = v;                  // pos 0..13
                    }
                } else if (c >= IMG - 1 - PAD && c <= IMG - 2) {
                    #pragma unroll
                    for (int j = 0; j < 4; ++j) {
                        const float v = q == 0 ? acc[j].x : q == 1 ? acc[j].y : q == 2 ? acc[j].z : acc[j].w;
                        s[(rg * 4 + j) * LDSS + (2 * (IMG - 1) + PAD - c)] = v;  // pos 270..283
                    }
                }
            }
        }
    }
    __syncthreads();

    // ---- Phase B: horizontal conv, LDS -> global. thread = (row 0..31, colgroup 0..15).
    //      lane = row within half-wave -> b128 column reads spread across all bank groups.
    {
        const int row = t & 31;
        const int cg  = t >> 5;          // 0..15
        const int c0  = cg * 16;

        float acc[16];
        #pragma unroll
        for (int c = 0; c < 16; ++c) acc[c] = 0.f;

        const float4* srow = (const float4*)&s[row * LDSS + c0];   // 16B-aligned
        #pragma unroll
        for (int m = 0; m < 11; ++m) {   // 44 floats = 11 x b128
            const float4 v4 = srow[m];
            #pragma unroll
            for (int q = 0; q < 4; ++q) {
                const int p = 4 * m + q;
                const float v = q == 0 ? v4.x : q == 1 ? v4.y : q == 2 ? v4.z : v4.w;
                #pragma unroll
                for (int c = 0; c < 16; ++c) {
                    const int k = p - c;
                    if (k >= 0 && k < KS) acc[c] += WT[k] * v;
                }
            }
        }

        float4* orow = (float4*)&dst[(size_t)(y0 + row) * IMG + c0];
        #pragma unroll
        for (int m = 0; m < 4; ++m)
            orow[m] = make_float4(acc[4*m+0], acc[4*m+1], acc[4*m+2], acc[4*m+3]);
    }
}

extern "C" void kernel_launch(void* const* d_in, const int* in_sizes, int n_in,
                              void* d_out, int out_size, void* d_ws, size_t ws_size,
                              hipStream_t stream) {
    const float* x = (const float*)d_in[0];
    float* out = (float*)d_out;
    const int images = in_sizes[0] / (IMG * IMG);   // 8*64 = 512
    dim3 grid(IMG / ROWS, images);                  // (8, 512)
    gauss_v4<<<grid, dim3(512), 0, stream>>>(x, out);
}